// Round 2
// baseline (2624.287 us; speedup 1.0000x reference)
//
#include <hip/hip_runtime.h>
#include <math.h>

typedef _Float16 half8 __attribute__((ext_vector_type(8)));
typedef float floatx4 __attribute__((ext_vector_type(4)));
typedef unsigned long long u64;

#define MFMA16(a, b, c) __builtin_amdgcn_mfma_f32_16x16x32_f16((a), (b), (c), 0, 0, 0)
#define SCOPE_AGENT __HIP_MEMORY_SCOPE_AGENT

static constexpr float C11 = 4.8828125e-4f;          // 2^-11
static constexpr float C22 = 2.384185791015625e-7f;  // 2^-22
static constexpr int LO = 128 * 264;                 // lo-page offset in ldsWih

// Scratch lives in device globals: no dependence on ws_size at all.
__device__ unsigned g_flags[128];       // [layer][group][slice]
__device__ unsigned g_exch[4096];       // [layer][parity][group][8 q][16 s]
__device__ unsigned g_bits[32768 * 8];  // layer-0 spikes, bit-packed [row][8 words]

__global__ void zero_flags_k() {
  if (threadIdx.x < 128) g_flags[threadIdx.x] = 0;
}

__device__ __forceinline__ unsigned ld_atomic(const unsigned* p) {
  return __hip_atomic_load(p, __ATOMIC_RELAXED, SCOPE_AGENT);
}
__device__ __forceinline__ void st_atomic(unsigned* p, unsigned v) {
  __hip_atomic_store(p, v, __ATOMIC_RELAXED, SCOPE_AGENT);
}

// f32 -> f16 hi + 2^11-scaled f16 lo. hi forced to 0 below f16-normal so no
// MFMA operand is ever subnormal (denorm-flush-proof); lo' is then normal and
// captures the value exactly to 2^-22 relative.
__device__ __forceinline__ void split16(float v, _Float16& hi, _Float16& lo) {
  _Float16 h = (fabsf(v) < 6.103515625e-05f) ? (_Float16)0.0f : (_Float16)v;
  hi = h;
  lo = (_Float16)((v - (float)h) * 2048.0f);
}

// One WG = (group g: 16 sequences) x (slice kwg: 32 hidden cols, all 4 gates).
// 8 groups x 8 slices = 64 WGs; wave wv = gate type. Binary h-slices exchanged
// between the 8 WGs of a group via agent-scope atomics + release/acquire flags.
template <int LAYER>
__global__ __launch_bounds__(256, 1) void scan_kernel(
    const float* __restrict__ x0,    // LAYER==0: [256*128][256] f32
    const float* __restrict__ wih,   // [1024][256] f32
    const float* __restrict__ whh,   // [1024][256] f32
    const float* __restrict__ bias,  // [1024] f32
    float* __restrict__ dout) {
  __shared__ __align__(16) _Float16 ldsWih[2 * 128 * 264];  // [hi|lo'][128 rows][256+8]
  __shared__ __align__(16) _Float16 lut[256 * 8];           // byte -> 8 x f16 {0,1}
  __shared__ unsigned hwLDS[128];
  __shared__ u64 spikeLDS[32];
  __shared__ u64 h64LDS[8];
  __shared__ u64 c64LDS[8];

  const int tid = threadIdx.x;
  const int lane = tid & 63;
  const int wv = tid >> 6;
  const int g = blockIdx.x & 7;
  const int kwg = blockIdx.x >> 3;
  const int m16 = lane & 15;
  const int l16 = lane >> 4;

  unsigned* exch = g_exch + LAYER * 2048;
  unsigned* flags = g_flags + LAYER * 64;

  // ---- stage W_ih slice into LDS, splitting f32 -> hi/lo' on the fly ----
  for (int t = tid; t < 4096; t += 256) {
    int nl = t >> 5, ci = t & 31;  // local row (gate*32+jloc), 8-elem chunk
    int grow = (nl >> 5) * 256 + 32 * kwg + (nl & 31);
    const float* src = wih + (size_t)grow * 256 + ci * 8;
    floatx4 v0 = *(const floatx4*)src;
    floatx4 v1 = *(const floatx4*)(src + 4);
    half8 hi, lo;
#pragma unroll
    for (int e = 0; e < 4; ++e) { _Float16 a, b; split16(v0[e], a, b); hi[e] = a; lo[e] = b; }
#pragma unroll
    for (int e = 0; e < 4; ++e) { _Float16 a, b; split16(v1[e], a, b); hi[4 + e] = a; lo[4 + e] = b; }
    *(half8*)(ldsWih + (size_t)nl * 264 + ci * 8) = hi;
    *(half8*)(ldsWih + LO + (size_t)nl * 264 + ci * 8) = lo;
  }
#pragma unroll
  for (int e = 0; e < 8; ++e)
    lut[tid * 8 + e] = ((tid >> e) & 1) ? (_Float16)1.0f : (_Float16)0.0f;

  // ---- persistent W_hh fragments in VGPRs (hi + scaled lo), 128 regs ----
  half8 BhhH[2][8], BhhL[2][8];
#pragma unroll
  for (int t2 = 0; t2 < 2; ++t2) {
    int grow = wv * 256 + 32 * kwg + t2 * 16 + m16;
#pragma unroll
    for (int q = 0; q < 8; ++q) {
      const float* src = whh + (size_t)grow * 256 + 32 * q + 8 * l16;
      floatx4 v0 = *(const floatx4*)src;
      floatx4 v1 = *(const floatx4*)(src + 4);
      half8 hi, lo;
#pragma unroll
      for (int e = 0; e < 4; ++e) { _Float16 a, b; split16(v0[e], a, b); hi[e] = a; lo[e] = b; }
#pragma unroll
      for (int e = 0; e < 4; ++e) { _Float16 a, b; split16(v1[e], a, b); hi[4 + e] = a; lo[4 + e] = b; }
      BhhH[t2][q] = hi;
      BhhL[t2][q] = lo;
    }
  }

  float bl[2];
#pragma unroll
  for (int t2 = 0; t2 < 2; ++t2) bl[t2] = bias[wv * 256 + 32 * kwg + t2 * 16 + m16];

  floatx4 a0A[2], a1A[2], a2A[2], a0B[2], a1B[2], a2B[2];
  floatx4 xr[16];  // LAYER0 x fragments
  unsigned xw[8];  // LAYER1 bit-words
  u64 cst = 0;
  bool dead = false;

  auto issue_x = [&](int ln) {
    if constexpr (LAYER == 0) {
      size_t base = ((size_t)ln * 128 + 16 * g + m16) * 256 + 8 * l16;
#pragma unroll
      for (int q = 0; q < 8; ++q) {
        xr[2 * q] = *(const floatx4*)(x0 + base + 32 * q);
        xr[2 * q + 1] = *(const floatx4*)(x0 + base + 32 * q + 4);
      }
    } else {
      size_t base = ((size_t)ln * 128 + 16 * g + m16) * 8;
#pragma unroll
      for (int q = 0; q < 8; ++q) xw[q] = g_bits[base + q];
    }
  };

  auto ih_compute = [&](floatx4(&A0)[2], floatx4(&A1)[2], floatx4(&A2)[2]) {
    floatx4 zz = {0.0f, 0.0f, 0.0f, 0.0f};
    A0[0] = A0[1] = zz; A1[0] = A1[1] = zz; A2[0] = A2[1] = zz;
#pragma unroll
    for (int q = 0; q < 8; ++q) {
      half8 ah, al;
      if constexpr (LAYER == 0) {
#pragma unroll
        for (int e = 0; e < 8; ++e) {
          float xv = (e < 4) ? xr[2 * q][e] : xr[2 * q + 1][e - 4];
          _Float16 hh, ll;
          split16(xv, hh, ll);
          ah[e] = hh; al[e] = ll;
        }
      } else {
        unsigned byt = (xw[q] >> (8 * l16)) & 0xFFu;
        ah = *(const half8*)(lut + byt * 8);
      }
#pragma unroll
      for (int t2 = 0; t2 < 2; ++t2) {
        int rbase = (32 * wv + t2 * 16 + m16) * 264 + 32 * q + 8 * l16;
        half8 whi = *(const half8*)(ldsWih + rbase);
        half8 wlo = *(const half8*)(ldsWih + LO + rbase);
        A0[t2] = MFMA16(ah, whi, A0[t2]);
        A1[t2] = MFMA16(ah, wlo, A1[t2]);
        if constexpr (LAYER == 0) {
          A1[t2] = MFMA16(al, whi, A1[t2]);
          A2[t2] = MFMA16(al, wlo, A2[t2]);
        }
      }
    }
  };

  auto step_body = [&](int l, floatx4(&u0)[2], floatx4(&u1)[2], floatx4(&u2)[2],
                       floatx4(&f0)[2], floatx4(&f1)[2], floatx4(&f2)[2]) {
    // (1) IH for step l+1 (hides the exchange wait), prefetch input l+2
    if (l < 255) {
      ih_compute(f0, f1, f2);
      int ln = l + 2;
      if (ln > 255) ln = 255;
      issue_x(ln);
    }
    // (2) obtain h(l) slices from the 8 WGs of this group
    if (l > 0) {
      if (wv == 0) {
        if (!dead) {
          unsigned tgt = (unsigned)l;
          const unsigned* fp = flags + g * 8 + (lane & 7);
          int it = 0;
          for (;;) {
            unsigned v = (lane < 8) ? ld_atomic(fp) : 0xFFFFFFFFu;
            if (__all((int)(v >= tgt))) break;
            if (++it > (1 << 24)) { dead = true; break; }  // bail, don't hang
          }
        }
        __builtin_amdgcn_fence(__ATOMIC_ACQUIRE, "agent");
        const unsigned* page = exch + (size_t)((l & 1) * 8 + g) * 128;
        hwLDS[lane] = ld_atomic(page + lane);
        hwLDS[64 + lane] = ld_atomic(page + 64 + lane);
      }
    }
    __syncthreads();
    // (3) recurrent matvec: LUT-expanded binary h x resident W_hh
    floatx4 ac0 = u0[0], ac1 = u0[1];
    floatx4 bc0 = u1[0], bc1 = u1[1];
    if (l > 0) {
#pragma unroll
      for (int q = 0; q < 8; ++q) {
        unsigned mw = hwLDS[q * 16 + m16];
        unsigned byt = (mw >> (8 * l16)) & 0xFFu;
        half8 af = *(const half8*)(lut + byt * 8);
        ac0 = MFMA16(af, BhhH[0][q], ac0);
        ac1 = MFMA16(af, BhhH[1][q], ac1);
        bc0 = MFMA16(af, BhhL[0][q], bc0);
        bc1 = MFMA16(af, BhhL[1][q], bc1);
      }
    }
    // (4) gates -> spikes -> bitwise c,h update
    u64 bal[2][4];
#pragma unroll
    for (int r = 0; r < 4; ++r) {
      float p0 = ac0[r] + bl[0] + C11 * bc0[r] + C22 * u2[0][r];
      float p1 = ac1[r] + bl[1] + C11 * bc1[r] + C22 * u2[1][r];
      bal[0][r] = __ballot(p0 >= 0.0f);
      bal[1][r] = __ballot(p1 >= 0.0f);
    }
    if (lane == 0) {
#pragma unroll
      for (int t2 = 0; t2 < 2; ++t2)
#pragma unroll
        for (int r = 0; r < 4; ++r) spikeLDS[wv * 8 + t2 * 4 + r] = bal[t2][r];
    }
    __syncthreads();
    {
      int idx = tid & 7;
      u64 iS = spikeLDS[idx], fS = spikeLDS[8 + idx];
      u64 gS = spikeLDS[16 + idx], oS = spikeLDS[24 + idx];
      cst = (fS & cst) | (iS & gS);  // c = min(f*c + i*g, 1) exactly
      u64 hS = oS & cst;             // h = o*c
      if (tid < 8) { h64LDS[tid] = hS; c64LDS[tid] = cst; }
    }
    __syncthreads();
    // (5) publish h(l+1) slice + outputs
    if (tid < 16) {
      int s = tid;
      int sh16 = 16 * (s >> 2);
      unsigned hu = (unsigned)((h64LDS[s & 3] >> sh16) & 0xFFFFull) |
                    ((unsigned)((h64LDS[4 + (s & 3)] >> sh16) & 0xFFFFull) << 16);
      if (l < 255)
        st_atomic(exch + (size_t)(((l + 1) & 1) * 8 + g) * 128 + kwg * 16 + s, hu);
      size_t row = (size_t)l * 128 + 16 * g + s;
      if constexpr (LAYER == 0) {
        g_bits[row * 8 + kwg] = hu;  // bit-packed layer-0 output
      } else {
        float* frow = dout + row * 256 + 32 * kwg;
#pragma unroll
        for (int c4 = 0; c4 < 8; ++c4) {
          floatx4 v;
#pragma unroll
          for (int j = 0; j < 4; ++j) v[j] = ((hu >> (c4 * 4 + j)) & 1) ? 1.0f : 0.0f;
          *(floatx4*)(frow + c4 * 4) = v;
        }
      }
      if (l == 255) {  // final states
        unsigned cu = (unsigned)((c64LDS[s & 3] >> sh16) & 0xFFFFull) |
                      ((unsigned)((c64LDS[4 + (s & 3)] >> sh16) & 0xFFFFull) << 16);
        float* shp = dout + 8388608 + LAYER * 32768 + (size_t)(16 * g + s) * 256 + 32 * kwg;
        float* scp = shp + 65536;
#pragma unroll
        for (int c4 = 0; c4 < 8; ++c4) {
          floatx4 vh, vc;
#pragma unroll
          for (int j = 0; j < 4; ++j) {
            vh[j] = ((hu >> (c4 * 4 + j)) & 1) ? 1.0f : 0.0f;
            vc[j] = ((cu >> (c4 * 4 + j)) & 1) ? 1.0f : 0.0f;
          }
          *(floatx4*)(shp + c4 * 4) = vh;
          *(floatx4*)(scp + c4 * 4) = vc;
        }
      }
    }
    __syncthreads();  // drains stores (vmcnt) before the flag release
    if (tid == 0 && l < 255)
      __hip_atomic_store(flags + g * 8 + kwg, (unsigned)(l + 1), __ATOMIC_RELEASE, SCOPE_AGENT);
  };

  // prologue
  issue_x(0);
  __syncthreads();  // W_ih + LUT ready
  ih_compute(a0A, a1A, a2A);
  issue_x(1);

#pragma unroll 1
  for (int l = 0; l < 256; l += 2) {
    step_body(l, a0A, a1A, a2A, a0B, a1B, a2B);
    step_body(l + 1, a0B, a1B, a2B, a0A, a1A, a2A);
  }
}

extern "C" void kernel_launch(void* const* d_in, const int* in_sizes, int n_in,
                              void* d_out, int out_size, void* d_ws, size_t ws_size,
                              hipStream_t stream) {
  (void)in_sizes; (void)n_in; (void)out_size; (void)d_ws; (void)ws_size;
  const float* x = (const float*)d_in[0];
  const float* wih0 = (const float*)d_in[1];
  const float* whh0 = (const float*)d_in[2];
  const float* b0 = (const float*)d_in[3];
  const float* wih1 = (const float*)d_in[4];
  const float* whh1 = (const float*)d_in[5];
  const float* b1 = (const float*)d_in[6];
  float* dout = (float*)d_out;

  zero_flags_k<<<1, 128, 0, stream>>>();
  scan_kernel<0><<<64, 256, 0, stream>>>(x, wih0, whh0, b0, dout);
  scan_kernel<1><<<64, 256, 0, stream>>>((const float*)nullptr, wih1, whh1, b1, dout);
}

// Round 4
// 1027.244 us; speedup vs baseline: 2.5547x; 2.5547x over previous
//
#include <hip/hip_runtime.h>
#include <math.h>

typedef _Float16 half8 __attribute__((ext_vector_type(8)));
typedef float floatx4 __attribute__((ext_vector_type(4)));
typedef unsigned long long u64;

#define MFMA16(a, b, c) __builtin_amdgcn_mfma_f32_16x16x32_f16((a), (b), (c), 0, 0, 0)
#define AARG __ATOMIC_RELAXED, __HIP_MEMORY_SCOPE_AGENT

static constexpr float C11 = 4.8828125e-4f;          // 2^-11
static constexpr float C22 = 2.384185791015625e-7f;  // 2^-22
static constexpr int LOPG = 128 * 264;               // lo-page offset in ldsWih

// Scratch in device globals (round-1 lesson: never depend on ws_size).
// Exchange atom: {tag = step (low 32) | h-bits (high 32)} — self-validating.
__device__ u64 g_exch[2 * 4 * 8 * 128];  // [layer][slot4][group][q*16+s]
__device__ _Float16 g_xhi[8388608];      // x hi/lo split planes
__device__ _Float16 g_xlo[8388608];

__global__ __launch_bounds__(256) void zero_k() {
  g_exch[blockIdx.x * 256 + threadIdx.x] = 0;  // grid 32
}

__device__ __forceinline__ u64 ald(const u64* p) {
  return __hip_atomic_load(p, AARG);
}
__device__ __forceinline__ void ast(u64* p, u64 v) {
  __hip_atomic_store(p, v, AARG);
}

// f32 -> normal-f16 hi + 2^11-scaled f16 lo (denorm-proof; round-2-verified).
__device__ __forceinline__ void split16(float v, _Float16& hi, _Float16& lo) {
  _Float16 h = (fabsf(v) < 6.103515625e-05f) ? (_Float16)0.0f : (_Float16)v;
  hi = h;
  lo = (_Float16)((v - (float)h) * 2048.0f);
}

__global__ __launch_bounds__(256) void presplit_k(const float* __restrict__ x) {
  int i = (blockIdx.x * 256 + threadIdx.x) * 8;
  floatx4 a = *(const floatx4*)(x + i);
  floatx4 b = *(const floatx4*)(x + i + 4);
  half8 hi, lo;
#pragma unroll
  for (int e = 0; e < 4; ++e) { _Float16 p, q; split16(a[e], p, q); hi[e] = p; lo[e] = q; }
#pragma unroll
  for (int e = 0; e < 4; ++e) { _Float16 p, q; split16(b[e], p, q); hi[4 + e] = p; lo[4 + e] = q; }
  *(half8*)(g_xhi + i) = hi;
  *(half8*)(g_xlo + i) = lo;
}

// One WG = (group g: 16 sequences) x (slice kwg: 32 hidden cols, all 4 gates).
// 8 groups x 8 slices x 2 layers = 128 WGs. Wave wv = gate type. L1 runs ~2
// steps behind L0, consuming L0's ring; ring depth 4 + exact tags +
// backpressure (L0 waits for L1 tag >= l-4 before clobbering).
template <int LAYER>
__device__ void scan_body(_Float16* ldsWih, _Float16* lut, unsigned* hwLDS,
                          u64* spikeLDS, const float* __restrict__ wih,
                          const float* __restrict__ whh,
                          const float* __restrict__ bias,
                          float* __restrict__ dout, int g, int kwg) {
  const int tid = threadIdx.x;
  const int lane = tid & 63;
  const int wv = tid >> 6;
  const int m16 = lane & 15;
  const int l16 = lane >> 4;

  u64* exch0 = g_exch;                  // layer-0 ring (L1 reads it)
  u64* exchMy = g_exch + LAYER * 4096;  // own ring
  u64* exchL1 = g_exch + 4096;          // layer-1 ring (L0 backpressure)

  // ---- stage W_ih slice into LDS (hi/lo split on the fly) ----
  for (int t = tid; t < 4096; t += 256) {
    int nl = t >> 5, ci = t & 31;
    int grow = (nl >> 5) * 256 + 32 * kwg + (nl & 31);
    const float* src = wih + (size_t)grow * 256 + ci * 8;
    floatx4 v0 = *(const floatx4*)src;
    floatx4 v1 = *(const floatx4*)(src + 4);
    half8 hi, lo;
#pragma unroll
    for (int e = 0; e < 4; ++e) { _Float16 p, q; split16(v0[e], p, q); hi[e] = p; lo[e] = q; }
#pragma unroll
    for (int e = 0; e < 4; ++e) { _Float16 p, q; split16(v1[e], p, q); hi[4 + e] = p; lo[4 + e] = q; }
    *(half8*)(ldsWih + (size_t)nl * 264 + ci * 8) = hi;
    *(half8*)(ldsWih + LOPG + (size_t)nl * 264 + ci * 8) = lo;
  }
#pragma unroll
  for (int e = 0; e < 8; ++e)
    lut[tid * 8 + e] = ((tid >> e) & 1) ? (_Float16)1.0f : (_Float16)0.0f;

  // ---- persistent W_hh fragments in VGPRs ----
  half8 BhhH[2][8], BhhL[2][8];
#pragma unroll
  for (int t2 = 0; t2 < 2; ++t2) {
    int grow = wv * 256 + 32 * kwg + t2 * 16 + m16;
#pragma unroll
    for (int q = 0; q < 8; ++q) {
      const float* src = whh + (size_t)grow * 256 + 32 * q + 8 * l16;
      floatx4 v0 = *(const floatx4*)src;
      floatx4 v1 = *(const floatx4*)(src + 4);
      half8 hi, lo;
#pragma unroll
      for (int e = 0; e < 4; ++e) { _Float16 p, q2; split16(v0[e], p, q2); hi[e] = p; lo[e] = q2; }
#pragma unroll
      for (int e = 0; e < 4; ++e) { _Float16 p, q2; split16(v1[e], p, q2); hi[4 + e] = p; lo[4 + e] = q2; }
      BhhH[t2][q] = hi;
      BhhL[t2][q] = lo;
    }
  }

  float bl[2];
#pragma unroll
  for (int t2 = 0; t2 < 2; ++t2) bl[t2] = bias[wv * 256 + 32 * kwg + t2 * 16 + m16];

  floatx4 A0a[2], A1a[2], A2a[2], A0b[2], A1b[2], A2b[2];
  half8 xrh[8], xrl[8];  // LAYER0 input fragments
  unsigned xw[8];        // LAYER1 bit-words
  u64 cst = 0;
  int polls = 0;
  const int POLL_MAX = 1 << 22;  // shared budget: bail visibly, never hang

  auto issue_x = [&](int ln) {  // LAYER 0 only
    size_t base = ((size_t)ln * 128 + 16 * g + m16) * 256 + 8 * l16;
#pragma unroll
    for (int q = 0; q < 8; ++q) {
      xrh[q] = *(const half8*)(g_xhi + base + 32 * q);
      xrl[q] = *(const half8*)(g_xlo + base + 32 * q);
    }
  };

  auto read_xw = [&](int tag) {  // LAYER 1: self-tagged input words (all waves)
    const u64* page = exch0 + (size_t)(tag & 3) * 1024 + g * 128 + m16;
    u64 v[8];
    for (;;) {
#pragma unroll
      for (int q = 0; q < 8; ++q) v[q] = ald(page + q * 16);
      bool ok = true;
#pragma unroll
      for (int q = 0; q < 8; ++q) ok = ok && ((unsigned)v[q] == (unsigned)tag);
      if (__all(ok)) break;
      if (++polls > POLL_MAX) break;
    }
#pragma unroll
    for (int q = 0; q < 8; ++q) xw[q] = (unsigned)(v[q] >> 32);
  };

  auto ih_compute = [&](floatx4(&A0)[2], floatx4(&A1)[2], floatx4(&A2)[2]) {
    floatx4 zz = {0.f, 0.f, 0.f, 0.f};
    A0[0] = A0[1] = zz; A1[0] = A1[1] = zz; A2[0] = A2[1] = zz;
#pragma unroll
    for (int q = 0; q < 8; ++q) {
      half8 ah, al;
      if constexpr (LAYER == 0) {
        ah = xrh[q];
        al = xrl[q];
      } else {
        unsigned byt = (xw[q] >> (8 * l16)) & 0xFFu;
        ah = *(const half8*)(lut + byt * 8);
      }
#pragma unroll
      for (int t2 = 0; t2 < 2; ++t2) {
        int rbase = (32 * wv + t2 * 16 + m16) * 264 + 32 * q + 8 * l16;
        half8 whi = *(const half8*)(ldsWih + rbase);
        half8 wlo = *(const half8*)(ldsWih + LOPG + rbase);
        A0[t2] = MFMA16(ah, whi, A0[t2]);
        A1[t2] = MFMA16(ah, wlo, A1[t2]);
        if constexpr (LAYER == 0) {
          A1[t2] = MFMA16(al, whi, A1[t2]);
          A2[t2] = MFMA16(al, wlo, A2[t2]);
        }
      }
    }
  };

  // 32 h-bits of sequence s=lane (<16), assembled from this wave's per-thread v
  auto gather16 = [&](u64 v) -> unsigned {
    unsigned a0 = __shfl((unsigned)v, lane & 3);
    unsigned a1 = __shfl((unsigned)(v >> 32), lane & 3);
    unsigned b0 = __shfl((unsigned)v, 4 + (lane & 3));
    unsigned b1 = __shfl((unsigned)(v >> 32), 4 + (lane & 3));
    u64 A = ((u64)a1 << 32) | a0;
    u64 B = ((u64)b1 << 32) | b0;
    int sh = 16 * ((lane & 15) >> 2);
    return (unsigned)((A >> sh) & 0xFFFFull) |
           ((unsigned)((B >> sh) & 0xFFFFull) << 16);
  };

  auto step_body = [&](int l, floatx4(&u0)[2], floatx4(&u1)[2], floatx4(&u2)[2],
                       floatx4(&f0)[2], floatx4(&f1)[2], floatx4(&f2)[2]) {
    // (1) IH for step l+1 (cross-layer wait lives here for L1)
    if (l < 255) {
      if constexpr (LAYER == 1) read_xw(l + 2);
      ih_compute(f0, f1, f2);
      if constexpr (LAYER == 0) issue_x(l + 2 > 255 ? 255 : l + 2);
    }
    // (2) recurrent h(l-1... actually h(l)) wait + read, wave0 only
    if (wv == 0 && l > 0) {
      int q = lane >> 3, sp = (lane & 7) * 2;
      const u64* base = exchMy + (size_t)(l & 3) * 1024 + g * 128 + q * 16 + sp;
      const u64* bp = exchL1 + (size_t)((l - 4) & 3) * 1024 + g * 128 + lane * 16;
      u64 v0, v1;
      for (;;) {
        v0 = ald(base);
        v1 = ald(base + 1);
        bool ok = ((unsigned)v0 == (unsigned)l) && ((unsigned)v1 == (unsigned)l);
        if (LAYER == 0 && l >= 4 && lane < 8)
          ok = ok && ((unsigned)ald(bp) >= (unsigned)(l - 4));  // backpressure
        if (__all(ok)) break;
        if (++polls > POLL_MAX) break;
      }
      hwLDS[q * 16 + sp] = (unsigned)(v0 >> 32);
      hwLDS[q * 16 + sp + 1] = (unsigned)(v1 >> 32);
    }
    __syncthreads();  // A: hwLDS ready
    // (3) recurrent matvec from VGPR-resident W_hh
    floatx4 ac0 = u0[0], ac1 = u0[1], bc0 = u1[0], bc1 = u1[1];
    if (l > 0) {
#pragma unroll
      for (int q = 0; q < 8; ++q) {
        unsigned mw = hwLDS[q * 16 + m16];
        unsigned byt = (mw >> (8 * l16)) & 0xFFu;
        half8 af = *(const half8*)(lut + byt * 8);
        ac0 = MFMA16(af, BhhH[0][q], ac0);
        ac1 = MFMA16(af, BhhH[1][q], ac1);
        bc0 = MFMA16(af, BhhL[0][q], bc0);
        bc1 = MFMA16(af, BhhL[1][q], bc1);
      }
    }
    // (4) gates -> spikes -> bitwise c,h update
    u64 bal[2][4];
#pragma unroll
    for (int r = 0; r < 4; ++r) {
      float p0 = ac0[r] + bl[0] + C11 * bc0[r] + C22 * u2[0][r];
      float p1 = ac1[r] + bl[1] + C11 * bc1[r] + C22 * u2[1][r];
      bal[0][r] = __ballot(p0 >= 0.0f);
      bal[1][r] = __ballot(p1 >= 0.0f);
    }
    if (lane == 0) {
#pragma unroll
      for (int t2 = 0; t2 < 2; ++t2)
#pragma unroll
        for (int r = 0; r < 4; ++r) spikeLDS[wv * 8 + t2 * 4 + r] = bal[t2][r];
    }
    __syncthreads();  // B: spikes ready
    {
      int idx = lane & 7;
      u64 iS = spikeLDS[idx], fS = spikeLDS[8 + idx];
      u64 gS = spikeLDS[16 + idx], oS = spikeLDS[24 + idx];
      cst = (fS & cst) | (iS & gS);  // c = min(f*c+i*g, 1) exactly
    }
    u64 hS = spikeLDS[24 + (lane & 7)] & cst;  // h = o*c
    // (5) wave0: publish {tag l+1 | h}; wave1: dout; wave2: final states
    if (wv == 0) {
      unsigned hu = gather16(hS);
      if (lane < 16)
        ast(exchMy + (size_t)((l + 1) & 3) * 1024 + g * 128 + kwg * 16 + lane,
            ((u64)hu << 32) | (unsigned)(l + 1));
    }
    if (LAYER == 1 && wv == 1) {
      unsigned hu = gather16(hS);
      if (lane < 16) {
        float* frow = dout + ((size_t)l * 128 + 16 * g + lane) * 256 + 32 * kwg;
#pragma unroll
        for (int c4 = 0; c4 < 8; ++c4) {
          floatx4 v;
#pragma unroll
          for (int j = 0; j < 4; ++j) v[j] = ((hu >> (c4 * 4 + j)) & 1) ? 1.0f : 0.0f;
          *(floatx4*)(frow + c4 * 4) = v;
        }
      }
    }
    if (l == 255 && wv == 2) {
      unsigned hu = gather16(hS);
      unsigned cu = gather16(cst);
      if (lane < 16) {
        float* shp = dout + 8388608 + LAYER * 32768 +
                     (size_t)(16 * g + lane) * 256 + 32 * kwg;
        float* scp = shp + 65536;
#pragma unroll
        for (int c4 = 0; c4 < 8; ++c4) {
          floatx4 vh, vc;
#pragma unroll
          for (int j = 0; j < 4; ++j) {
            vh[j] = ((hu >> (c4 * 4 + j)) & 1) ? 1.0f : 0.0f;
            vc[j] = ((cu >> (c4 * 4 + j)) & 1) ? 1.0f : 0.0f;
          }
          *(floatx4*)(shp + c4 * 4) = vh;
          *(floatx4*)(scp + c4 * 4) = vc;
        }
      }
    }
  };

  // ---- prologue ----
  if constexpr (LAYER == 0) {
    issue_x(0);
    __syncthreads();  // ldsWih + lut ready
    ih_compute(A0a, A1a, A2a);
    issue_x(1);
  } else {
    __syncthreads();  // ldsWih + lut ready
    read_xw(1);       // h0(0)
    ih_compute(A0a, A1a, A2a);
  }

#pragma unroll 1
  for (int l = 0; l < 256; l += 2) {
    step_body(l, A0a, A1a, A2a, A0b, A1b, A2b);
    step_body(l + 1, A0b, A1b, A2b, A0a, A1a, A2a);
  }
}

__global__ __launch_bounds__(256, 1) void spike_scan(
    const float* __restrict__ wih0, const float* __restrict__ whh0,
    const float* __restrict__ b0, const float* __restrict__ wih1,
    const float* __restrict__ whh1, const float* __restrict__ b1,
    float* __restrict__ dout) {
  __shared__ __align__(16) _Float16 ldsWih[2 * 128 * 264];
  __shared__ __align__(16) _Float16 lut[256 * 8];
  __shared__ unsigned hwLDS[128];
  __shared__ u64 spikeLDS[32];

  int bi = blockIdx.x;
  int g = bi & 7;
  int kwg = (bi >> 3) & 7;
  if ((bi >> 6) == 0)
    scan_body<0>(ldsWih, lut, hwLDS, spikeLDS, wih0, whh0, b0, dout, g, kwg);
  else
    scan_body<1>(ldsWih, lut, hwLDS, spikeLDS, wih1, whh1, b1, dout, g, kwg);
}

extern "C" void kernel_launch(void* const* d_in, const int* in_sizes, int n_in,
                              void* d_out, int out_size, void* d_ws, size_t ws_size,
                              hipStream_t stream) {
  (void)in_sizes; (void)n_in; (void)out_size; (void)d_ws; (void)ws_size;
  const float* x = (const float*)d_in[0];
  const float* wih0 = (const float*)d_in[1];
  const float* whh0 = (const float*)d_in[2];
  const float* b0 = (const float*)d_in[3];
  const float* wih1 = (const float*)d_in[4];
  const float* whh1 = (const float*)d_in[5];
  const float* b1 = (const float*)d_in[6];
  float* dout = (float*)d_out;

  zero_k<<<32, 256, 0, stream>>>();
  presplit_k<<<4096, 256, 0, stream>>>(x);
  spike_scan<<<128, 256, 0, stream>>>(wih0, whh0, b0, wih1, whh1, b1, dout);
}

// Round 5
// 978.150 us; speedup vs baseline: 2.6829x; 1.0502x over previous
//
#include <hip/hip_runtime.h>
#include <math.h>

typedef _Float16 half8 __attribute__((ext_vector_type(8)));
typedef float floatx4 __attribute__((ext_vector_type(4)));
typedef unsigned long long u64;

#define MFMA16(a, b, c) __builtin_amdgcn_mfma_f32_16x16x32_f16((a), (b), (c), 0, 0, 0)
#define AARG __ATOMIC_RELAXED, __HIP_MEMORY_SCOPE_AGENT

static constexpr float C11 = 4.8828125e-4f;          // 2^-11
static constexpr float C22 = 2.384185791015625e-7f;  // 2^-22
static constexpr int LOPG = 128 * 264;               // lo-page offset in ldsWih
static constexpr int SLOTS = 257;                    // deep ring: one slot per step
static constexpr int LSTRIDE = SLOTS * 8 * 128;      // atoms per layer

// Scratch in device globals (round-1 lesson: never depend on ws_size).
// Exchange atom: {tag = step (low 32) | h-bits (high 32)} — self-validating.
// Deep ring: every slot written exactly once per launch -> no backpressure,
// no L0<->L1 coupling, no ring-wrap hazard.
__device__ u64 g_exch[2 * LSTRIDE];  // [layer][slot][group][q*16+s]
__device__ _Float16 g_xhi[8388608];  // x hi/lo split planes
__device__ _Float16 g_xlo[8388608];

__global__ __launch_bounds__(256) void zero_k() {
  unsigned i = blockIdx.x * 256 + threadIdx.x;  // grid 2056 = 526336/256
  if (i < 2 * LSTRIDE) g_exch[i] = 0;
}

__device__ __forceinline__ u64 ald(const u64* p) {
  return __hip_atomic_load(p, AARG);
}
__device__ __forceinline__ void ast(u64* p, u64 v) {
  __hip_atomic_store(p, v, AARG);
}

// f32 -> normal-f16 hi + 2^11-scaled f16 lo (denorm-proof; round-2-verified).
__device__ __forceinline__ void split16(float v, _Float16& hi, _Float16& lo) {
  _Float16 h = (fabsf(v) < 6.103515625e-05f) ? (_Float16)0.0f : (_Float16)v;
  hi = h;
  lo = (_Float16)((v - (float)h) * 2048.0f);
}

__global__ __launch_bounds__(256) void presplit_k(const float* __restrict__ x) {
  int i = (blockIdx.x * 256 + threadIdx.x) * 8;
  floatx4 a = *(const floatx4*)(x + i);
  floatx4 b = *(const floatx4*)(x + i + 4);
  half8 hi, lo;
#pragma unroll
  for (int e = 0; e < 4; ++e) { _Float16 p, q; split16(a[e], p, q); hi[e] = p; lo[e] = q; }
#pragma unroll
  for (int e = 0; e < 4; ++e) { _Float16 p, q; split16(b[e], p, q); hi[4 + e] = p; lo[4 + e] = q; }
  *(half8*)(g_xhi + i) = hi;
  *(half8*)(g_xlo + i) = lo;
}

// One WG = (group g: 16 sequences) x (slice kwg: 32 hidden cols, all 4 gates).
// 8 groups x 8 slices x 2 layers = 128 WGs. Wave wv = gate type. L1 trails L0,
// consuming L0's ring; deep ring + exact tags, zero coupling back to L0.
template <int LAYER>
__device__ void scan_body(_Float16* ldsWih, _Float16* lut, unsigned* hwLDS,
                          u64* spikeLDS, const float* __restrict__ wih,
                          const float* __restrict__ whh,
                          const float* __restrict__ bias,
                          float* __restrict__ dout, int g, int kwg) {
  const int tid = threadIdx.x;
  const int lane = tid & 63;
  const int wv = tid >> 6;
  const int m16 = lane & 15;
  const int l16 = lane >> 4;

  u64* exch0 = g_exch;                      // layer-0 ring (L1 reads it)
  u64* exchMy = g_exch + LAYER * LSTRIDE;   // own ring

  // ---- stage W_ih slice into LDS (hi/lo split on the fly) ----
  for (int t = tid; t < 4096; t += 256) {
    int nl = t >> 5, ci = t & 31;
    int grow = (nl >> 5) * 256 + 32 * kwg + (nl & 31);
    const float* src = wih + (size_t)grow * 256 + ci * 8;
    floatx4 v0 = *(const floatx4*)src;
    floatx4 v1 = *(const floatx4*)(src + 4);
    half8 hi, lo;
#pragma unroll
    for (int e = 0; e < 4; ++e) { _Float16 p, q; split16(v0[e], p, q); hi[e] = p; lo[e] = q; }
#pragma unroll
    for (int e = 0; e < 4; ++e) { _Float16 p, q; split16(v1[e], p, q); hi[4 + e] = p; lo[4 + e] = q; }
    *(half8*)(ldsWih + (size_t)nl * 264 + ci * 8) = hi;
    *(half8*)(ldsWih + LOPG + (size_t)nl * 264 + ci * 8) = lo;
  }
#pragma unroll
  for (int e = 0; e < 8; ++e)
    lut[tid * 8 + e] = ((tid >> e) & 1) ? (_Float16)1.0f : (_Float16)0.0f;

  // ---- persistent W_hh fragments in VGPRs ----
  half8 BhhH[2][8], BhhL[2][8];
#pragma unroll
  for (int t2 = 0; t2 < 2; ++t2) {
    int grow = wv * 256 + 32 * kwg + t2 * 16 + m16;
#pragma unroll
    for (int q = 0; q < 8; ++q) {
      const float* src = whh + (size_t)grow * 256 + 32 * q + 8 * l16;
      floatx4 v0 = *(const floatx4*)src;
      floatx4 v1 = *(const floatx4*)(src + 4);
      half8 hi, lo;
#pragma unroll
      for (int e = 0; e < 4; ++e) { _Float16 p, q2; split16(v0[e], p, q2); hi[e] = p; lo[e] = q2; }
#pragma unroll
      for (int e = 0; e < 4; ++e) { _Float16 p, q2; split16(v1[e], p, q2); hi[4 + e] = p; lo[4 + e] = q2; }
      BhhH[t2][q] = hi;
      BhhL[t2][q] = lo;
    }
  }

  float bl[2];
#pragma unroll
  for (int t2 = 0; t2 < 2; ++t2) bl[t2] = bias[wv * 256 + 32 * kwg + t2 * 16 + m16];

  floatx4 A0a[2], A1a[2], A2a[2], A0b[2], A1b[2], A2b[2];
  half8 xrh[8], xrl[8];  // LAYER0 input fragments
  unsigned xw[8];        // LAYER1 bit-words
  u64 cst = 0;
  int polls = 0;
  const int POLL_MAX = 1 << 22;  // shared budget: bail visibly, never hang

  auto issue_x = [&](int ln) {  // LAYER 0 only
    size_t base = ((size_t)ln * 128 + 16 * g + m16) * 256 + 8 * l16;
#pragma unroll
    for (int q = 0; q < 8; ++q) {
      xrh[q] = *(const half8*)(g_xhi + base + 32 * q);
      xrl[q] = *(const half8*)(g_xlo + base + 32 * q);
    }
  };

  auto read_xw = [&](int tag) {  // LAYER 1: self-tagged input words (all waves)
    const u64* page = exch0 + (size_t)tag * 1024 + g * 128 + m16;
    u64 v[8];
    for (;;) {
#pragma unroll
      for (int q = 0; q < 8; ++q) v[q] = ald(page + q * 16);
      bool ok = true;
#pragma unroll
      for (int q = 0; q < 8; ++q) ok = ok && ((unsigned)v[q] == (unsigned)tag);
      if (__all(ok)) break;
      if (++polls > POLL_MAX) break;
    }
#pragma unroll
    for (int q = 0; q < 8; ++q) xw[q] = (unsigned)(v[q] >> 32);
  };

  auto ih_compute = [&](floatx4(&A0)[2], floatx4(&A1)[2], floatx4(&A2)[2]) {
    floatx4 zz = {0.f, 0.f, 0.f, 0.f};
    A0[0] = A0[1] = zz; A1[0] = A1[1] = zz; A2[0] = A2[1] = zz;
#pragma unroll
    for (int q = 0; q < 8; ++q) {
      half8 ah, al;
      if constexpr (LAYER == 0) {
        ah = xrh[q];
        al = xrl[q];
      } else {
        unsigned byt = (xw[q] >> (8 * l16)) & 0xFFu;
        ah = *(const half8*)(lut + byt * 8);
      }
#pragma unroll
      for (int t2 = 0; t2 < 2; ++t2) {
        int rbase = (32 * wv + t2 * 16 + m16) * 264 + 32 * q + 8 * l16;
        half8 whi = *(const half8*)(ldsWih + rbase);
        half8 wlo = *(const half8*)(ldsWih + LOPG + rbase);
        A0[t2] = MFMA16(ah, whi, A0[t2]);
        A1[t2] = MFMA16(ah, wlo, A1[t2]);
        if constexpr (LAYER == 0) {
          A1[t2] = MFMA16(al, whi, A1[t2]);
          A2[t2] = MFMA16(al, wlo, A2[t2]);
        }
      }
    }
  };

  // 32 h-bits of sequence s=lane (<16), assembled from this wave's per-thread v
  auto gather16 = [&](u64 v) -> unsigned {
    unsigned a0 = __shfl((unsigned)v, lane & 3);
    unsigned a1 = __shfl((unsigned)(v >> 32), lane & 3);
    unsigned b0 = __shfl((unsigned)v, 4 + (lane & 3));
    unsigned b1 = __shfl((unsigned)(v >> 32), 4 + (lane & 3));
    u64 A = ((u64)a1 << 32) | a0;
    u64 B = ((u64)b1 << 32) | b0;
    int sh = 16 * ((lane & 15) >> 2);
    return (unsigned)((A >> sh) & 0xFFFFull) |
           ((unsigned)((B >> sh) & 0xFFFFull) << 16);
  };

  auto step_body = [&](int l, floatx4(&u0)[2], floatx4(&u1)[2], floatx4(&u2)[2],
                       floatx4(&f0)[2], floatx4(&f1)[2], floatx4(&f2)[2]) {
    // (1) IH for step l+1 (cross-layer wait lives here for L1; never spins in
    // steady state since L0 runs ahead)
    if (l < 255) {
      if constexpr (LAYER == 1) read_xw(l + 2);
      ih_compute(f0, f1, f2);
      if constexpr (LAYER == 0) issue_x(l + 2 > 255 ? 255 : l + 2);
    }
    // (2) own-ring wait + read for h(l), wave0 only
    if (wv == 0 && l > 0) {
      const u64* base = exchMy + (size_t)l * 1024 + g * 128 + 2 * lane;
      u64 v0, v1;
      for (;;) {
        v0 = ald(base);
        v1 = ald(base + 1);
        bool ok = ((unsigned)v0 == (unsigned)l) && ((unsigned)v1 == (unsigned)l);
        if (__all(ok)) break;
        if (++polls > POLL_MAX) break;
      }
      hwLDS[2 * lane] = (unsigned)(v0 >> 32);
      hwLDS[2 * lane + 1] = (unsigned)(v1 >> 32);
    }
    __syncthreads();  // A: hwLDS ready
    // (3) recurrent matvec from VGPR-resident W_hh
    floatx4 ac0 = u0[0], ac1 = u0[1], bc0 = u1[0], bc1 = u1[1];
    if (l > 0) {
#pragma unroll
      for (int q = 0; q < 8; ++q) {
        unsigned mw = hwLDS[q * 16 + m16];
        unsigned byt = (mw >> (8 * l16)) & 0xFFu;
        half8 af = *(const half8*)(lut + byt * 8);
        ac0 = MFMA16(af, BhhH[0][q], ac0);
        ac1 = MFMA16(af, BhhH[1][q], ac1);
        bc0 = MFMA16(af, BhhL[0][q], bc0);
        bc1 = MFMA16(af, BhhL[1][q], bc1);
      }
    }
    // (4) gates -> spikes -> bitwise c,h update
    u64 bal[2][4];
#pragma unroll
    for (int r = 0; r < 4; ++r) {
      float p0 = ac0[r] + bl[0] + C11 * bc0[r] + C22 * u2[0][r];
      float p1 = ac1[r] + bl[1] + C11 * bc1[r] + C22 * u2[1][r];
      bal[0][r] = __ballot(p0 >= 0.0f);
      bal[1][r] = __ballot(p1 >= 0.0f);
    }
    if (lane == 0) {
#pragma unroll
      for (int t2 = 0; t2 < 2; ++t2)
#pragma unroll
        for (int r = 0; r < 4; ++r) spikeLDS[wv * 8 + t2 * 4 + r] = bal[t2][r];
    }
    __syncthreads();  // B: spikes ready
    {
      int idx = lane & 7;
      u64 iS = spikeLDS[idx], fS = spikeLDS[8 + idx];
      u64 gS = spikeLDS[16 + idx], oS = spikeLDS[24 + idx];
      cst = (fS & cst) | (iS & gS);  // c = min(f*c+i*g, 1) exactly
    }
    u64 hS = spikeLDS[24 + (lane & 7)] & cst;  // h = o*c
    // (5) wave0: publish {h | tag l+1} at slot l+1; wave1: dout; wave2: states
    if (wv == 0) {
      unsigned hu = gather16(hS);
      if (lane < 16)
        ast(exchMy + (size_t)(l + 1) * 1024 + g * 128 + kwg * 16 + lane,
            ((u64)hu << 32) | (unsigned)(l + 1));
    }
    if (LAYER == 1 && wv == 1) {
      unsigned hu = gather16(hS);
      if (lane < 16) {
        float* frow = dout + ((size_t)l * 128 + 16 * g + lane) * 256 + 32 * kwg;
#pragma unroll
        for (int c4 = 0; c4 < 8; ++c4) {
          floatx4 v;
#pragma unroll
          for (int j = 0; j < 4; ++j) v[j] = ((hu >> (c4 * 4 + j)) & 1) ? 1.0f : 0.0f;
          *(floatx4*)(frow + c4 * 4) = v;
        }
      }
    }
    if (l == 255 && wv == 2) {
      unsigned hu = gather16(hS);
      unsigned cu = gather16(cst);
      if (lane < 16) {
        float* shp = dout + 8388608 + LAYER * 32768 +
                     (size_t)(16 * g + lane) * 256 + 32 * kwg;
        float* scp = shp + 65536;
#pragma unroll
        for (int c4 = 0; c4 < 8; ++c4) {
          floatx4 vh, vc;
#pragma unroll
          for (int j = 0; j < 4; ++j) {
            vh[j] = ((hu >> (c4 * 4 + j)) & 1) ? 1.0f : 0.0f;
            vc[j] = ((cu >> (c4 * 4 + j)) & 1) ? 1.0f : 0.0f;
          }
          *(floatx4*)(shp + c4 * 4) = vh;
          *(floatx4*)(scp + c4 * 4) = vc;
        }
      }
    }
  };

  // ---- prologue ----
  if constexpr (LAYER == 0) {
    issue_x(0);
    __syncthreads();  // ldsWih + lut ready
    ih_compute(A0a, A1a, A2a);
    issue_x(1);
  } else {
    __syncthreads();  // ldsWih + lut ready
    read_xw(1);       // h0(0)
    ih_compute(A0a, A1a, A2a);
  }

#pragma unroll 1
  for (int l = 0; l < 256; l += 2) {
    step_body(l, A0a, A1a, A2a, A0b, A1b, A2b);
    step_body(l + 1, A0b, A1b, A2b, A0a, A1a, A2a);
  }
}

__global__ __launch_bounds__(256, 1) void spike_scan(
    const float* __restrict__ wih0, const float* __restrict__ whh0,
    const float* __restrict__ b0, const float* __restrict__ wih1,
    const float* __restrict__ whh1, const float* __restrict__ b1,
    float* __restrict__ dout) {
  __shared__ __align__(16) _Float16 ldsWih[2 * 128 * 264];
  __shared__ __align__(16) _Float16 lut[256 * 8];
  __shared__ unsigned hwLDS[128];
  __shared__ u64 spikeLDS[32];

  int bi = blockIdx.x;
  int g = bi & 7;
  int kwg = (bi >> 3) & 7;
  if ((bi >> 6) == 0)
    scan_body<0>(ldsWih, lut, hwLDS, spikeLDS, wih0, whh0, b0, dout, g, kwg);
  else
    scan_body<1>(ldsWih, lut, hwLDS, spikeLDS, wih1, whh1, b1, dout, g, kwg);
}

extern "C" void kernel_launch(void* const* d_in, const int* in_sizes, int n_in,
                              void* d_out, int out_size, void* d_ws, size_t ws_size,
                              hipStream_t stream) {
  (void)in_sizes; (void)n_in; (void)out_size; (void)d_ws; (void)ws_size;
  const float* x = (const float*)d_in[0];
  const float* wih0 = (const float*)d_in[1];
  const float* whh0 = (const float*)d_in[2];
  const float* b0 = (const float*)d_in[3];
  const float* wih1 = (const float*)d_in[4];
  const float* whh1 = (const float*)d_in[5];
  const float* b1 = (const float*)d_in[6];
  float* dout = (float*)d_out;

  zero_k<<<2056, 256, 0, stream>>>();
  presplit_k<<<4096, 256, 0, stream>>>(x);
  spike_scan<<<128, 256, 0, stream>>>(wih0, whh0, b0, wih1, whh1, b1, dout);
}